// Round 1
// baseline (856.252 us; speedup 1.0000x reference)
//
#include <hip/hip_runtime.h>

#define NCLS 100
#define EPS 1e-7f
#define ROWS_PER_BLOCK 512   // must be multiple of 64
#define N_ITER (ROWS_PER_BLOCK / 64)

// d_ws layout: counts[0..99]=pred_count, [100..199]=true_count, [200..299]=tp,
//              counts[300]=block-completion ticket
__global__ void zero_counts_kernel(unsigned int* __restrict__ counts) {
    int i = threadIdx.x;
    if (i < 3 * NCLS + 1) counts[i] = 0u;
}

__device__ __forceinline__ void load7(const float4* __restrict__ f4,
                                      int r, int q, int rowEnd,
                                      float4 v[7], int* lab,
                                      const int* __restrict__ labels) {
    if (r < rowEnd) {
        const size_t A = ((size_t)r * 25) & ~(size_t)3;
        #pragma unroll
        for (int k = 0; k < 7; ++k) v[k] = f4[A + 4 * k + q];
        if (q == 0) *lab = labels[r];
    }
}

__device__ __forceinline__ void process7(const float4 v[7], int r, int q,
                                         int rowEnd, int lab,
                                         unsigned int* s_pred,
                                         unsigned int* s_true,
                                         unsigned int* s_tp) {
    float best = -INFINITY;
    int bidx = 0;
    if (r < rowEnd) {
        const int r3 = r & 3;                 // = 25r mod 4
        const int off = (q - r3) << 2;
        #pragma unroll
        for (int k = 0; k < 7; ++k) {
            const int cb = 16 * k + off;      // col of element 0 of v[k]
            float4 w = v[k];
            if ((unsigned)(cb + 0) < (unsigned)NCLS && w.x > best) { best = w.x; bidx = cb;     }
            if ((unsigned)(cb + 1) < (unsigned)NCLS && w.y > best) { best = w.y; bidx = cb + 1; }
            if ((unsigned)(cb + 2) < (unsigned)NCLS && w.z > best) { best = w.z; bidx = cb + 2; }
            if ((unsigned)(cb + 3) < (unsigned)NCLS && w.w > best) { best = w.w; bidx = cb + 3; }
        }
    }
    // Quad-wide argmax (validity is quad-uniform): greater wins; tie -> lower col.
    #pragma unroll
    for (int m = 1; m <= 2; m <<= 1) {
        float ob = __shfl_xor(best, m, 64);
        int   oi = __shfl_xor(bidx, m, 64);
        if (ob > best || (ob == best && oi < bidx)) { best = ob; bidx = oi; }
    }
    if (q == 0 && r < rowEnd) {
        atomicAdd(&s_pred[bidx], 1u);
        atomicAdd(&s_true[lab], 1u);
        if (bidx == lab) atomicAdd(&s_tp[lab], 1u);
    }
}

__global__ __launch_bounds__(256) void hist_kernel(
        const float* __restrict__ logits,
        const int* __restrict__ labels,
        unsigned int* __restrict__ counts,
        float* __restrict__ out,
        int N, int numBlocks) {
    __shared__ unsigned int s_pred[NCLS];
    __shared__ unsigned int s_true[NCLS];
    __shared__ unsigned int s_tp[NCLS];
    for (int i = threadIdx.x; i < NCLS; i += blockDim.x) {
        s_pred[i] = 0u; s_true[i] = 0u; s_tp[i] = 0u;
    }
    __syncthreads();

    const int lane = threadIdx.x & 63;
    const int wv   = threadIdx.x >> 6;    // wave in block, 0..3
    const int q    = lane & 3;            // lane in quad
    const int g    = lane >> 2;           // quad in wave, 0..15

    const int blockStart = blockIdx.x * ROWS_PER_BLOCK;
    const int rowEnd     = min(blockStart + ROWS_PER_BLOCK, N);

    const float4* f4 = (const float4*)logits;

    // Wave w handles rows blockStart + w*16 + g + 64*i  (block advances by a
    // dense 64-row / 25.6KB window per iteration; blocks own contiguous chunks).
    int row = blockStart + wv * 16 + g;

    float4 va[7], vb[7];
    int la = 0, lb = 0;

    load7(f4, row, q, rowEnd, va, &la, labels);

    // 2-deep pipeline, manually unrolled x2 to avoid register copies.
    #pragma unroll 1
    for (int i = 0; i < N_ITER; i += 2) {
        const int r1 = row + 64;
        load7(f4, r1, q, rowEnd, vb, &lb, labels);        // in flight during...
        process7(va, row, q, rowEnd, la, s_pred, s_true, s_tp);

        const int r2 = r1 + 64;
        if (i + 2 < N_ITER) {
            load7(f4, r2, q, rowEnd, va, &la, labels);    // in flight during...
        }
        process7(vb, r1, q, rowEnd, lb, s_pred, s_true, s_tp);

        row = r2;
    }

    __syncthreads();
    for (int i = threadIdx.x; i < NCLS; i += blockDim.x) {
        unsigned int v;
        if ((v = s_pred[i]) != 0u) atomicAdd(&counts[i], v);
        if ((v = s_true[i]) != 0u) atomicAdd(&counts[NCLS + i], v);
        if ((v = s_tp[i])   != 0u) atomicAdd(&counts[2 * NCLS + i], v);
    }

    // ---- fold finalize into the last block (saves one launch + graph gap) ----
    __threadfence();                       // release: flush our count atomics
    __shared__ unsigned int s_ticket;
    if (threadIdx.x == 0)
        s_ticket = atomicAdd(&counts[3 * NCLS], 1u);   // device-scope RMW
    __syncthreads();                       // s_ticket visible block-wide (uniform)
    if (s_ticket != (unsigned int)(numBlocks - 1)) return;

    // We are the last block: every other block's ticket RMW (and, by its
    // preceding __threadfence, its count atomics) is ordered before our RMW.
    __threadfence();                       // acquire side
    __shared__ float s_f1[NCLS];
    const int c = threadIdx.x;
    if (c < NCLS) {
        float tp    = (float)__hip_atomic_load(&counts[2 * NCLS + c], __ATOMIC_RELAXED, __HIP_MEMORY_SCOPE_AGENT);
        float predc = (float)__hip_atomic_load(&counts[c],            __ATOMIC_RELAXED, __HIP_MEMORY_SCOPE_AGENT);
        float truec = (float)__hip_atomic_load(&counts[NCLS + c],     __ATOMIC_RELAXED, __HIP_MEMORY_SCOPE_AGENT);
        float fp = predc - tp;
        float fn = truec - tp;
        float precision = tp / (tp + fp + EPS);
        float recall    = tp / (tp + fn + EPS);
        float f1 = 2.0f * precision * recall / (precision + recall + EPS);
        s_f1[c] = f1;
    }
    __syncthreads();
    if (c == 0) {
        float sum = 0.0f;
        for (int i = 0; i < NCLS; ++i) sum += s_f1[i];
        out[0] = sum / (float)NCLS;
    }
}

extern "C" void kernel_launch(void* const* d_in, const int* in_sizes, int n_in,
                              void* d_out, int out_size, void* d_ws, size_t ws_size,
                              hipStream_t stream) {
    const float* logits = (const float*)d_in[0];
    const int*   labels = (const int*)d_in[1];
    float* out = (float*)d_out;
    unsigned int* counts = (unsigned int*)d_ws;  // 301 u32 scratch

    const int N = in_sizes[1];  // 1,000,000 rows

    zero_counts_kernel<<<1, 320, 0, stream>>>(counts);

    const int block = 256;
    const int grid  = (N + ROWS_PER_BLOCK - 1) / ROWS_PER_BLOCK;  // 1954
    hist_kernel<<<grid, block, 0, stream>>>(logits, labels, counts, out, N, grid);
}

// Round 2
// 562.739 us; speedup vs baseline: 1.5216x; 1.5216x over previous
//
#include <hip/hip_runtime.h>

#define NCLS 100
#define EPS 1e-7f
#define ROWS_PER_BLOCK 512   // must be multiple of 64
#define N_ITER (ROWS_PER_BLOCK / 64)

// d_ws layout: counts[0..99]=pred_count, [100..199]=true_count, [200..299]=tp
__global__ void zero_counts_kernel(unsigned int* __restrict__ counts) {
    int i = threadIdx.x;
    if (i < 3 * NCLS) counts[i] = 0u;
}

// Wave-dense window load: 16 rows = 400 float4 = 6.4 KB contiguous.
// Instr k: lanes 0..63 read f4[base + 64k + lane] -> one dense 1-KB burst.
__device__ __forceinline__ void loadwin(const float4* __restrict__ f4,
                                        const int* __restrict__ labels,
                                        int rowBase, int rowEnd, int lane,
                                        float4 v[7], int* lab) {
    const int rows = rowEnd - rowBase;
    if (rows <= 0) return;
    const int maxj = (rows >= 16) ? 400 : rows * 25;
    const size_t base = (size_t)rowBase * 25;   // float4 units; 400B-aligned
    #pragma unroll
    for (int k = 0; k < 7; ++k) {
        const int j = 64 * k + lane;
        if (j < maxj) v[k] = f4[base + j];
    }
    if (lane < 16 && lane < rows) *lab = labels[rowBase + lane];
}

// Per-window argmax via packed-key LDS max: key = flip(float)<<32 | (127-col).
// flip() is the standard monotone float->uint map; equal values -> larger
// (127-col) wins -> lower col, matching jnp.argmax first-max semantics.
__device__ __forceinline__ void procwin(const float4 v[7],
                                        int rowBase, int rowEnd,
                                        int lane, int lab,
                                        unsigned long long* __restrict__ s_win, // [16], per-wave
                                        unsigned int* __restrict__ s_pred,
                                        unsigned int* __restrict__ s_true,
                                        unsigned int* __restrict__ s_tp) {
    const int rows = rowEnd - rowBase;
    if (rows <= 0) return;
    const int maxj = (rows >= 16) ? 400 : rows * 25;

    if (lane < 16) s_win[lane] = 0ull;   // per-wave private; DS ops in program order

    #pragma unroll
    for (int k = 0; k < 7; ++k) {
        const int j = 64 * k + lane;
        if (j < maxj) {
            const int rl = j / 25;        // row within window (0..15)
            const int fq = j - rl * 25;   // float4 index within row (0..24)
            const int cb = fq << 2;       // column of element 0
            const float4 w = v[k];
            float bv = w.x; int bc = cb;
            if (w.y > bv) { bv = w.y; bc = cb + 1; }
            if (w.z > bv) { bv = w.z; bc = cb + 2; }
            if (w.w > bv) { bv = w.w; bc = cb + 3; }
            unsigned ku = __float_as_uint(bv);
            ku = (ku & 0x80000000u) ? ~ku : (ku | 0x80000000u);
            const unsigned long long pk =
                ((unsigned long long)ku << 32) | (unsigned)(127 - bc);
            atomicMax(&s_win[rl], pk);    // ds_max_u64, no return
        }
    }

    if (lane < 16 && lane < rows) {
        const unsigned long long pk = s_win[lane];  // compiler waits lgkm
        const int col = 127 - (int)(pk & 0xFFull);
        atomicAdd(&s_pred[col], 1u);
        atomicAdd(&s_true[lab], 1u);
        if (col == lab) atomicAdd(&s_tp[lab], 1u);
    }
}

__global__ __launch_bounds__(256) void hist_kernel(
        const float* __restrict__ logits,
        const int* __restrict__ labels,
        unsigned int* __restrict__ counts,
        int N) {
    __shared__ unsigned int s_pred[NCLS];
    __shared__ unsigned int s_true[NCLS];
    __shared__ unsigned int s_tp[NCLS];
    __shared__ unsigned long long s_win[4][16];   // per-wave argmax windows
    for (int i = threadIdx.x; i < NCLS; i += blockDim.x) {
        s_pred[i] = 0u; s_true[i] = 0u; s_tp[i] = 0u;
    }
    __syncthreads();

    const int lane = threadIdx.x & 63;
    const int wv   = threadIdx.x >> 6;    // wave in block, 0..3

    const int blockStart = blockIdx.x * ROWS_PER_BLOCK;
    const int rowEnd     = min(blockStart + ROWS_PER_BLOCK, N);

    const float4* f4 = (const float4*)logits;

    // Wave wv owns 16-row windows at blockStart + wv*16 + 64*i; the block's
    // 4 waves cover a dense 64-row / 25.6 KB region per iteration.
    int rowBase = blockStart + wv * 16;

    float4 va[7], vb[7];
    int la = 0, lb = 0;

    loadwin(f4, labels, rowBase, rowEnd, lane, va, &la);

    // 2-deep pipeline, manually unrolled x2 to avoid register copies.
    #pragma unroll 1
    for (int i = 0; i < N_ITER; i += 2) {
        const int r1 = rowBase + 64;
        loadwin(f4, labels, r1, rowEnd, lane, vb, &lb);   // in flight during...
        procwin(va, rowBase, rowEnd, lane, la, s_win[wv], s_pred, s_true, s_tp);

        const int r2 = r1 + 64;
        if (i + 2 < N_ITER) {
            loadwin(f4, labels, r2, rowEnd, lane, va, &la);
        }
        procwin(vb, r1, rowEnd, lane, lb, s_win[wv], s_pred, s_true, s_tp);

        rowBase = r2;
    }

    __syncthreads();
    for (int i = threadIdx.x; i < NCLS; i += blockDim.x) {
        unsigned int v;
        if ((v = s_pred[i]) != 0u) atomicAdd(&counts[i], v);
        if ((v = s_true[i]) != 0u) atomicAdd(&counts[NCLS + i], v);
        if ((v = s_tp[i])   != 0u) atomicAdd(&counts[2 * NCLS + i], v);
    }
}

__global__ void finalize_kernel(const unsigned int* __restrict__ counts,
                                float* __restrict__ out) {
    __shared__ float s_f1[NCLS];
    int c = threadIdx.x;
    if (c < NCLS) {
        float tp    = (float)counts[2 * NCLS + c];
        float predc = (float)counts[c];            // tp + fp
        float truec = (float)counts[NCLS + c];     // tp + fn
        float fp = predc - tp;
        float fn = truec - tp;
        float precision = tp / (tp + fp + EPS);
        float recall    = tp / (tp + fn + EPS);
        float f1 = 2.0f * precision * recall / (precision + recall + EPS);
        s_f1[c] = f1;
    }
    __syncthreads();
    if (c == 0) {
        float sum = 0.0f;
        for (int i = 0; i < NCLS; ++i) sum += s_f1[i];
        out[0] = sum / (float)NCLS;
    }
}

extern "C" void kernel_launch(void* const* d_in, const int* in_sizes, int n_in,
                              void* d_out, int out_size, void* d_ws, size_t ws_size,
                              hipStream_t stream) {
    const float* logits = (const float*)d_in[0];
    const int*   labels = (const int*)d_in[1];
    float* out = (float*)d_out;
    unsigned int* counts = (unsigned int*)d_ws;  // 300 u32 = 1200 B scratch

    const int N = in_sizes[1];  // 1,000,000 rows

    zero_counts_kernel<<<1, 320, 0, stream>>>(counts);

    const int block = 256;
    const int grid  = (N + ROWS_PER_BLOCK - 1) / ROWS_PER_BLOCK;  // 1954
    hist_kernel<<<grid, block, 0, stream>>>(logits, labels, counts, N);

    finalize_kernel<<<1, 128, 0, stream>>>(counts, out);
}

// Round 3
// 525.995 us; speedup vs baseline: 1.6279x; 1.0699x over previous
//
#include <hip/hip_runtime.h>

#define NCLS 100
#define EPS 1e-7f
#define ROWS_PER_BLOCK 512   // must be multiple of 64
#define N_ITER (ROWS_PER_BLOCK / 64)   // 8 windows of 16 rows per wave

// d_ws layout: counts[0..99]=pred_count, [100..199]=true_count, [200..299]=tp
__global__ void zero_counts_kernel(unsigned int* __restrict__ counts) {
    int i = threadIdx.x;
    if (i < 3 * NCLS) counts[i] = 0u;
}

__device__ __forceinline__ void load7(const float4* __restrict__ f4,
                                      int r, int q, int rowEnd,
                                      float4 v[7], int* lab,
                                      const int* __restrict__ labels) {
    if (r < rowEnd) {
        const size_t A = ((size_t)r * 25) & ~(size_t)3;
        #pragma unroll
        for (int k = 0; k < 7; ++k) v[k] = f4[A + 4 * k + q];
        if (q == 0) *lab = labels[r];
    }
}

__device__ __forceinline__ void process7(const float4 v[7], int r, int q,
                                         int rowEnd, int lab,
                                         unsigned int* s_pred,
                                         unsigned int* s_true,
                                         unsigned int* s_tp) {
    float best = -INFINITY;
    int bidx = 0;
    if (r < rowEnd) {
        const int r3 = r & 3;                 // = 25r mod 4
        const int off = (q - r3) << 2;
        #pragma unroll
        for (int k = 0; k < 7; ++k) {
            const int cb = 16 * k + off;      // col of element 0 of v[k]
            float4 w = v[k];
            if ((unsigned)(cb + 0) < (unsigned)NCLS && w.x > best) { best = w.x; bidx = cb;     }
            if ((unsigned)(cb + 1) < (unsigned)NCLS && w.y > best) { best = w.y; bidx = cb + 1; }
            if ((unsigned)(cb + 2) < (unsigned)NCLS && w.z > best) { best = w.z; bidx = cb + 2; }
            if ((unsigned)(cb + 3) < (unsigned)NCLS && w.w > best) { best = w.w; bidx = cb + 3; }
        }
    }
    // Quad-wide argmax (validity is quad-uniform): greater wins; tie -> lower col.
    #pragma unroll
    for (int m = 1; m <= 2; m <<= 1) {
        float ob = __shfl_xor(best, m, 64);
        int   oi = __shfl_xor(bidx, m, 64);
        if (ob > best || (ob == best && oi < bidx)) { best = ob; bidx = oi; }
    }
    if (q == 0 && r < rowEnd) {
        atomicAdd(&s_pred[bidx], 1u);
        atomicAdd(&s_true[lab], 1u);
        if (bidx == lab) atomicAdd(&s_tp[lab], 1u);
    }
}

// __launch_bounds__(256, 3): cap at ~170 VGPR so 3 waves/SIMD (12 waves/CU)
// co-reside with the 4-deep / ~112-VGPR load pipeline.
__global__ __launch_bounds__(256, 3) void hist_kernel(
        const float* __restrict__ logits,
        const int* __restrict__ labels,
        unsigned int* __restrict__ counts,
        int N) {
    __shared__ unsigned int s_pred[NCLS];
    __shared__ unsigned int s_true[NCLS];
    __shared__ unsigned int s_tp[NCLS];
    for (int i = threadIdx.x; i < NCLS; i += blockDim.x) {
        s_pred[i] = 0u; s_true[i] = 0u; s_tp[i] = 0u;
    }
    __syncthreads();

    const int lane = threadIdx.x & 63;
    const int wv   = threadIdx.x >> 6;    // wave in block, 0..3
    const int q    = lane & 3;            // lane in quad
    const int g    = lane >> 2;           // quad in wave, 0..15

    const int blockStart = blockIdx.x * ROWS_PER_BLOCK;
    const int rowEnd     = min(blockStart + ROWS_PER_BLOCK, N);

    const float4* f4 = (const float4*)logits;

    // Wave wv handles rows blockStart + wv*16 + g + 64*i: 8 windows of 16 rows.
    const int r0 = blockStart + wv * 16 + g;

    // 4-deep register pipeline: windows i, i+1, i+2, i+3 in flight while
    // processing window i. Slack between issue and drain of a batch is
    // ~3 process phases (~1300 cyc) > HBM-miss latency (~900 cyc), so waves
    // stop stalling on vmcnt and memory stays continuously requested.
    float4 va[7], vb[7], vc[7], vd[7];
    int la = 0, lb = 0, lc = 0, ld = 0;

    load7(f4, r0,       q, rowEnd, va, &la, labels);
    load7(f4, r0 + 64,  q, rowEnd, vb, &lb, labels);
    load7(f4, r0 + 128, q, rowEnd, vc, &lc, labels);
    load7(f4, r0 + 192, q, rowEnd, vd, &ld, labels);

    #pragma unroll 1
    for (int i = 0; i < N_ITER; i += 4) {
        const int r = r0 + 64 * i;

        process7(va, r, q, rowEnd, la, s_pred, s_true, s_tp);
        if (i + 4 < N_ITER) load7(f4, r + 256, q, rowEnd, va, &la, labels);

        process7(vb, r + 64, q, rowEnd, lb, s_pred, s_true, s_tp);
        if (i + 4 < N_ITER) load7(f4, r + 320, q, rowEnd, vb, &lb, labels);

        process7(vc, r + 128, q, rowEnd, lc, s_pred, s_true, s_tp);
        if (i + 4 < N_ITER) load7(f4, r + 384, q, rowEnd, vc, &lc, labels);

        process7(vd, r + 192, q, rowEnd, ld, s_pred, s_true, s_tp);
        if (i + 4 < N_ITER) load7(f4, r + 448, q, rowEnd, vd, &ld, labels);
    }

    __syncthreads();
    for (int i = threadIdx.x; i < NCLS; i += blockDim.x) {
        unsigned int v;
        if ((v = s_pred[i]) != 0u) atomicAdd(&counts[i], v);
        if ((v = s_true[i]) != 0u) atomicAdd(&counts[NCLS + i], v);
        if ((v = s_tp[i])   != 0u) atomicAdd(&counts[2 * NCLS + i], v);
    }
}

__global__ void finalize_kernel(const unsigned int* __restrict__ counts,
                                float* __restrict__ out) {
    __shared__ float s_f1[NCLS];
    int c = threadIdx.x;
    if (c < NCLS) {
        float tp    = (float)counts[2 * NCLS + c];
        float predc = (float)counts[c];            // tp + fp
        float truec = (float)counts[NCLS + c];     // tp + fn
        float fp = predc - tp;
        float fn = truec - tp;
        float precision = tp / (tp + fp + EPS);
        float recall    = tp / (tp + fn + EPS);
        float f1 = 2.0f * precision * recall / (precision + recall + EPS);
        s_f1[c] = f1;
    }
    __syncthreads();
    if (c == 0) {
        float sum = 0.0f;
        for (int i = 0; i < NCLS; ++i) sum += s_f1[i];
        out[0] = sum / (float)NCLS;
    }
}

extern "C" void kernel_launch(void* const* d_in, const int* in_sizes, int n_in,
                              void* d_out, int out_size, void* d_ws, size_t ws_size,
                              hipStream_t stream) {
    const float* logits = (const float*)d_in[0];
    const int*   labels = (const int*)d_in[1];
    float* out = (float*)d_out;
    unsigned int* counts = (unsigned int*)d_ws;  // 300 u32 = 1200 B scratch

    const int N = in_sizes[1];  // 1,000,000 rows

    zero_counts_kernel<<<1, 320, 0, stream>>>(counts);

    const int block = 256;
    const int grid  = (N + ROWS_PER_BLOCK - 1) / ROWS_PER_BLOCK;  // 1954
    hist_kernel<<<grid, block, 0, stream>>>(logits, labels, counts, N);

    finalize_kernel<<<1, 128, 0, stream>>>(counts, out);
}